// Round 5
// baseline (625.966 us; speedup 1.0000x reference)
//
#include <hip/hip_runtime.h>
#include <math.h>

// Problem constants (from reference)
#define N_NODES 100000
#define N_EDGES 1600000
#define E2      (N_NODES + N_EDGES)   // edges incl. self-loops = 1,700,000
#define IN_C    128
#define HID     64
#define HEADS   4
#define HH      256                    // HEADS*HID
#define OUT_C   2
#define NEG_SLOPE 0.2f

#define SB   1024                      // elements per scan block
#define NSB  ((N_NODES + SB - 1) / SB) // 98

__device__ __forceinline__ float bf2f(unsigned short u) {
    return __uint_as_float(((unsigned)u) << 16);
}
__device__ __forceinline__ unsigned short f2bf(float f) {
    unsigned u = __float_as_uint(f);
    u += 0x7fffu + ((u >> 16) & 1u);   // RNE
    return (unsigned short)(u >> 16);
}

// ---------------- CSR build ----------------

__global__ void k_hist(const int* __restrict__ ei, int* __restrict__ cnt) {
    int i = blockIdx.x * 256 + threadIdx.x;
    if (i >= E2) return;
    int d = (i < N_EDGES) ? ei[N_EDGES + i] : (i - N_EDGES);
    atomicAdd(&cnt[d], 1);
}

// multi-block exclusive scan: scan1 (block sums) -> scan2 (scan sums) -> scan3
__global__ __launch_bounds__(256) void k_scan1(const int* __restrict__ cnt,
                                               int* __restrict__ bsum) {
    int b = blockIdx.x, t = threadIdx.x;
    int i = b * SB + t * 4;
    int s = 0;
    if (i + 3 < N_NODES) {
        int4 v = *(const int4*)(cnt + i);
        s = (v.x + v.y) + (v.z + v.w);
    } else {
        for (int k = 0; k < 4; ++k) if (i + k < N_NODES) s += cnt[i + k];
    }
#pragma unroll
    for (int off = 1; off < 64; off <<= 1) s += __shfl_xor(s, off);
    __shared__ int wsum[4];
    int lane = t & 63, wv = t >> 6;
    if (lane == 0) wsum[wv] = s;
    __syncthreads();
    if (t == 0) bsum[b] = (wsum[0] + wsum[1]) + (wsum[2] + wsum[3]);
}

__global__ __launch_bounds__(128) void k_scan2(int* __restrict__ bsum) {
    __shared__ int sh[128];
    int t = threadIdx.x;
    int v = (t < NSB) ? bsum[t] : 0;
    sh[t] = v;
    __syncthreads();
    for (int off = 1; off < 128; off <<= 1) {
        int u = (t >= off) ? sh[t - off] : 0;
        __syncthreads();
        sh[t] += u;
        __syncthreads();
    }
    if (t < NSB) bsum[t] = sh[t] - v;  // exclusive
}

__global__ __launch_bounds__(256) void k_scan3(const int* __restrict__ cnt,
        const int* __restrict__ bsum, int* __restrict__ rowptr,
        float* __restrict__ dinv) {
    int b = blockIdx.x, t = threadIdx.x;
    int lane = t & 63, wv = t >> 6;
    int i = b * SB + t * 4;
    int c0 = 0, c1 = 0, c2 = 0, c3 = 0;
    if (i + 3 < N_NODES) {
        int4 v = *(const int4*)(cnt + i);
        c0 = v.x; c1 = v.y; c2 = v.z; c3 = v.w;
    } else if (i < N_NODES) {
        c0 = cnt[i];
        if (i + 1 < N_NODES) c1 = cnt[i + 1];
        if (i + 2 < N_NODES) c2 = cnt[i + 2];
    }
    int s = (c0 + c1) + (c2 + c3);
    int inc = s;
#pragma unroll
    for (int off = 1; off < 64; off <<= 1) {
        int u = __shfl_up(inc, off);
        if (lane >= off) inc += u;
    }
    __shared__ int wtot[4];
    if (lane == 63) wtot[wv] = inc;
    __syncthreads();
    int base = bsum[b] + (inc - s);
    for (int w = 0; w < wv; ++w) base += wtot[w];
    if (i < N_NODES)     { rowptr[i]     = base;               dinv[i]     = rsqrtf((float)c0); }
    if (i + 1 < N_NODES) { rowptr[i + 1] = base + c0;           dinv[i + 1] = rsqrtf((float)c1); }
    if (i + 2 < N_NODES) { rowptr[i + 2] = base + c0 + c1;      dinv[i + 2] = rsqrtf((float)c2); }
    if (i + 3 < N_NODES) { rowptr[i + 3] = base + c0 + c1 + c2; dinv[i + 3] = rsqrtf((float)c3); }
    if (b == 0 && t == 0) rowptr[N_NODES] = E2;
}

__global__ void k_fill(const int* __restrict__ ei, const int* __restrict__ rowptr,
                       int* __restrict__ cur, int* __restrict__ col) {
    int i = blockIdx.x * 256 + threadIdx.x;
    if (i >= E2) return;
    int s, d;
    if (i < N_EDGES) { s = ei[i]; d = ei[N_EDGES + i]; }
    else             { s = d = i - N_EDGES; }
    int pos = rowptr[d] + atomicAdd(&cur[d], 1);
    col[pos] = s;
}

// ---------------- ws precompute: wsd[k][o] -----------------------------------
__global__ void k_prews(const float* __restrict__ W2, const float* __restrict__ att_src,
                        const float* __restrict__ att_dst, float* __restrict__ wsd) {
    int t = blockIdx.x * 64 + threadIdx.x;   // 512 total
    int k = t >> 3, o = t & 7;
    int h = o & 3;
    const float* att = (o < 4) ? att_src : att_dst;
    float acc = 0.f;
    const float* wrow = W2 + (size_t)k * HH + h * 64;
    const float* arow = att + h * 64;
    for (int c = 0; c < 64; ++c) acc = fmaf(wrow[c], arow[c], acc);
    wsd[k * 8 + o] = acc;
}

// ---------------- GEMM1: xw1b = bf16((x @ W1) * dinv[row])  [N,64] ----------
__global__ __launch_bounds__(256) void k_gemm1(const float* __restrict__ x,
        const float* __restrict__ W1, const float* __restrict__ dinv,
        unsigned short* __restrict__ xw1b) {
    __shared__ float xs[32 * IN_C];  // 16 KB
    int t = threadIdx.x;
    int r0 = blockIdx.x * 32;        // grid = N/32, exact
    const float4* xg = (const float4*)(x + (size_t)r0 * IN_C);
    float4* xs4 = (float4*)xs;
#pragma unroll
    for (int i = 0; i < 4; ++i) xs4[i * 256 + t] = xg[i * 256 + t];
    int lane = t & 63, wv = t >> 6;
    float w[IN_C];
#pragma unroll
    for (int k = 0; k < IN_C; ++k) w[k] = W1[k * HID + lane];
    __syncthreads();
    for (int j0 = 0; j0 < 8; j0 += 2) {
        int ja = wv * 8 + j0, jb = ja + 1;
        const float4* xa = (const float4*)(xs + ja * IN_C);
        const float4* xb = (const float4*)(xs + jb * IN_C);
        float aA = 0.f, aB = 0.f;
#pragma unroll
        for (int kk = 0; kk < 32; ++kk) {
            float4 va = xa[kk], vb = xb[kk];
            aA = fmaf(va.x, w[4 * kk + 0], aA);
            aA = fmaf(va.y, w[4 * kk + 1], aA);
            aA = fmaf(va.z, w[4 * kk + 2], aA);
            aA = fmaf(va.w, w[4 * kk + 3], aA);
            aB = fmaf(vb.x, w[4 * kk + 0], aB);
            aB = fmaf(vb.y, w[4 * kk + 1], aB);
            aB = fmaf(vb.z, w[4 * kk + 2], aB);
            aB = fmaf(vb.w, w[4 * kk + 3], aB);
        }
        int ra = r0 + ja, rb = r0 + jb;
        xw1b[(size_t)ra * HID + lane] = f2bf(aA * dinv[ra]);
        xw1b[(size_t)rb * HID + lane] = f2bf(aB * dinv[rb]);
    }
}

// ---------------- GCN1 aggregate: h1 = relu(dinv[d]*sum_s xw1[s] + b1) ------
// wave per dst; 16 lanes per edge (ushort4 = 4 bf16 ch/lane), 4 edges/group.
__global__ __launch_bounds__(256) void k_agg1(const int* __restrict__ rowptr,
        const int* __restrict__ col, const unsigned short* __restrict__ xw1b,
        const float* __restrict__ dinv, const float* __restrict__ b1,
        float* __restrict__ h1) {
    int t = threadIdx.x;
    int lane = t & 63;
    int d = blockIdx.x * 4 + (t >> 6);
    if (d >= N_NODES) return;
    int start = rowptr[d], end = rowptr[d + 1];
    int sub = lane >> 4;       // which of 4 edges in a group
    int cpos = lane & 15;      // channel quad (4 bf16)
    float4 acc = make_float4(0.f, 0.f, 0.f, 0.f);
    for (int base = start; base < end; base += 64) {
        int cnt = min(64, end - base);
        int sl = (base + lane < end) ? col[base + lane] : 0;
#pragma unroll 4
        for (int j = 0; j < cnt; j += 4) {
            int idx = j + sub;
            int sj = __shfl(sl, idx);
            if (idx < cnt) {
                ushort4 v = ((const ushort4*)(xw1b + (size_t)sj * HID))[cpos];
                acc.x += bf2f(v.x); acc.y += bf2f(v.y);
                acc.z += bf2f(v.z); acc.w += bf2f(v.w);
            }
        }
    }
    acc.x += __shfl_xor(acc.x, 16); acc.y += __shfl_xor(acc.y, 16);
    acc.z += __shfl_xor(acc.z, 16); acc.w += __shfl_xor(acc.w, 16);
    acc.x += __shfl_xor(acc.x, 32); acc.y += __shfl_xor(acc.y, 32);
    acc.z += __shfl_xor(acc.z, 32); acc.w += __shfl_xor(acc.w, 32);
    if (lane < 16) {
        float di = dinv[d];
        float4 b = ((const float4*)b1)[lane];
        float4 o;
        o.x = fmaf(acc.x, di, b.x); o.x = o.x > 0.f ? o.x : 0.f;
        o.y = fmaf(acc.y, di, b.y); o.y = o.y > 0.f ? o.y : 0.f;
        o.z = fmaf(acc.z, di, b.z); o.z = o.z > 0.f ? o.z : 0.f;
        o.w = fmaf(acc.w, di, b.w); o.w = o.w > 0.f ? o.w : 0.f;
        ((float4*)(h1 + (size_t)d * HID))[lane] = o;
    }
}

// ---------------- GEMM2: xw2b = bf16(h1 @ W2) [n][c*4+h], a_s, a_d ----------
__global__ __launch_bounds__(256) void k_gemm2(const float* __restrict__ h1,
        const float* __restrict__ W2, const float* __restrict__ wsd,
        unsigned short* __restrict__ xw2b, float* __restrict__ a_s,
        float* __restrict__ a_d) {
    __shared__ float hs[32 * HID];   // 8 KB
    __shared__ float ws[512];        // 2 KB
    int t = threadIdx.x;
    int r0 = blockIdx.x * 32;        // grid = N/32, exact
    const float4* hg = (const float4*)(h1 + (size_t)r0 * HID);
    float4* hs4 = (float4*)hs;
#pragma unroll
    for (int i = 0; i < 2; ++i) hs4[i * 256 + t] = hg[i * 256 + t];
    ((float2*)ws)[t] = ((const float2*)wsd)[t];
    float w[HID];
#pragma unroll
    for (int k = 0; k < HID; ++k) w[k] = W2[k * HH + t];
    __syncthreads();
    int lane = t & 63, h = t >> 6;
    for (int j = 0; j < 32; j += 2) {
        const float4* ha = (const float4*)(hs + j * HID);
        const float4* hb = (const float4*)(hs + (j + 1) * HID);
        float aA = 0.f, aB = 0.f;
#pragma unroll
        for (int kk = 0; kk < 16; ++kk) {
            float4 va = ha[kk], vb = hb[kk];
            aA = fmaf(va.x, w[4 * kk + 0], aA);
            aA = fmaf(va.y, w[4 * kk + 1], aA);
            aA = fmaf(va.z, w[4 * kk + 2], aA);
            aA = fmaf(va.w, w[4 * kk + 3], aA);
            aB = fmaf(vb.x, w[4 * kk + 0], aB);
            aB = fmaf(vb.y, w[4 * kk + 1], aB);
            aB = fmaf(vb.z, w[4 * kk + 2], aB);
            aB = fmaf(vb.w, w[4 * kk + 3], aB);
        }
        xw2b[(size_t)(r0 + j) * HH + lane * 4 + h] = f2bf(aA);
        xw2b[(size_t)(r0 + j + 1) * HH + lane * 4 + h] = f2bf(aB);
    }
    {
        int j = t >> 3, o = t & 7;
        const float* hrow = hs + j * HID;
        float acc = 0.f;
#pragma unroll
        for (int k = 0; k < 64; ++k) {
            int ke = (k + j) & 63;
            acc = fmaf(hrow[ke], ws[ke * 8 + o], acc);
        }
        int r = r0 + j;
        if (o < 4) a_s[r * 4 + o] = acc;
        else       a_d[r * 4 + (o - 4)] = acc;
    }
}

// ---------------- GAT aggregate + ELU + fused GEMM3 -------------------------
__global__ __launch_bounds__(256) void k_agg2(const int* __restrict__ rowptr,
        const int* __restrict__ col, const unsigned short* __restrict__ xw2b,
        const float* __restrict__ a_s, const float* __restrict__ a_d,
        const float* __restrict__ b2, const float* __restrict__ W3,
        const float* __restrict__ dinv, float2* __restrict__ xw3) {
    __shared__ int   ss[4][64];      // 1 KB
    __shared__ float sp[4][64][4];   // 4 KB
    int t = threadIdx.x;
    int lane = t & 63, wv = t >> 6;
    int d = blockIdx.x * 4 + wv;
    if (d >= N_NODES) return;
    const float4* as4 = (const float4*)a_s;
    float4 adv = ((const float4*)a_d)[d];
    int start = rowptr[d], end = rowptr[d + 1];

    float den0 = 0.f, den1 = 0.f, den2 = 0.f, den3 = 0.f;
    float acc0 = 0.f, acc1 = 0.f, acc2 = 0.f, acc3 = 0.f;
    const ushort4* xw24 = (const ushort4*)xw2b;      // row = 64 ushort4
    for (int base = start; base < end; base += 64) {
        int cnt = min(64, end - base);
        float p0 = 0.f, p1 = 0.f, p2 = 0.f, p3 = 0.f;
        int s = 0;
        if (lane < cnt) {
            s = col[base + lane];
            float4 av = as4[s];
            float v;
            v = av.x + adv.x; v = v > 0.f ? v : NEG_SLOPE * v; p0 = __expf(v);
            v = av.y + adv.y; v = v > 0.f ? v : NEG_SLOPE * v; p1 = __expf(v);
            v = av.z + adv.z; v = v > 0.f ? v : NEG_SLOPE * v; p2 = __expf(v);
            v = av.w + adv.w; v = v > 0.f ? v : NEG_SLOPE * v; p3 = __expf(v);
            den0 += p0; den1 += p1; den2 += p2; den3 += p3;
        }
        ss[wv][lane] = s;                                  // wave-private LDS
        ((float4*)sp[wv])[lane] = make_float4(p0, p1, p2, p3);
#pragma unroll 8
        for (int j = 0; j < cnt; ++j) {
            int sj = ss[wv][j];                            // broadcast read
            float4 pj = ((const float4*)sp[wv])[j];        // broadcast read
            ushort4 xv = xw24[(size_t)sj * 64 + lane];     // 8B/lane coalesced
            acc0 = fmaf(pj.x, bf2f(xv.x), acc0);
            acc1 = fmaf(pj.y, bf2f(xv.y), acc1);
            acc2 = fmaf(pj.z, bf2f(xv.z), acc2);
            acc3 = fmaf(pj.w, bf2f(xv.w), acc3);
        }
    }
#pragma unroll
    for (int mk = 1; mk < 64; mk <<= 1) {
        den0 += __shfl_xor(den0, mk);
        den1 += __shfl_xor(den1, mk);
        den2 += __shfl_xor(den2, mk);
        den3 += __shfl_xor(den3, mk);
    }

    float o0 = acc0 / (den0 + 1e-16f) + b2[lane];
    float o1 = acc1 / (den1 + 1e-16f) + b2[64 + lane];
    float o2 = acc2 / (den2 + 1e-16f) + b2[128 + lane];
    float o3 = acc3 / (den3 + 1e-16f) + b2[192 + lane];
    o0 = o0 > 0.f ? o0 : expm1f(o0);
    o1 = o1 > 0.f ? o1 : expm1f(o1);
    o2 = o2 > 0.f ? o2 : expm1f(o2);
    o3 = o3 > 0.f ? o3 : expm1f(o3);
    const float2* w32 = (const float2*)W3;     // W3[256][2]
    float2 w0 = w32[lane], w1 = w32[64 + lane];
    float2 w2 = w32[128 + lane], w3 = w32[192 + lane];
    float px = o0 * w0.x + o1 * w1.x + o2 * w2.x + o3 * w3.x;
    float py = o0 * w0.y + o1 * w1.y + o2 * w2.y + o3 * w3.y;
#pragma unroll
    for (int mk = 1; mk < 64; mk <<= 1) {
        px += __shfl_xor(px, mk);
        py += __shfl_xor(py, mk);
    }
    if (lane == 0) {
        float di = dinv[d];
        xw3[d] = make_float2(px * di, py * di);
    }
}

// ---------------- GCN2 aggregate: out = dinv[d]*sum_s xw3[s] + b3 -----------
__global__ void k_agg3(const int* __restrict__ rowptr, const int* __restrict__ col,
        const float2* __restrict__ xw3, const float* __restrict__ dinv,
        const float* __restrict__ b3, float* __restrict__ out) {
    int d = blockIdx.x * 256 + threadIdx.x;
    if (d >= N_NODES) return;
    int e = rowptr[d], end = rowptr[d + 1];
    float a0 = 0.f, a1 = 0.f;
    for (; e < end; ++e) {
        float2 v = xw3[col[e]];
        a0 += v.x; a1 += v.y;
    }
    float di = dinv[d];
    out[d * 2 + 0] = fmaf(a0, di, b3[0]);
    out[d * 2 + 1] = fmaf(a1, di, b3[1]);
}

// ---------------- launch ----------------

extern "C" void kernel_launch(void* const* d_in, const int* in_sizes, int n_in,
                              void* d_out, int out_size, void* d_ws, size_t ws_size,
                              hipStream_t stream) {
    const float* x       = (const float*)d_in[0];
    const int*   ei      = (const int*)d_in[1];
    const float* W1      = (const float*)d_in[2];
    const float* b1      = (const float*)d_in[3];
    const float* W2      = (const float*)d_in[4];
    const float* att_src = (const float*)d_in[5];
    const float* att_dst = (const float*)d_in[6];
    const float* b2      = (const float*)d_in[7];
    const float* W3      = (const float*)d_in[8];
    const float* b3      = (const float*)d_in[9];
    float* out = (float*)d_out;
    (void)in_sizes; (void)n_in; (void)out_size; (void)ws_size;

    char* ws = (char*)d_ws;
    size_t off = 0;
    auto alloc = [&](size_t bytes) -> void* {
        void* p = ws + off;
        off = (off + bytes + 255) & ~(size_t)255;
        return p;
    };
    int*    rowptr = (int*)alloc((N_NODES + 1) * sizeof(int));
    int*    cnt    = (int*)alloc(N_NODES * sizeof(int));
    int*    bsum   = (int*)alloc(NSB * sizeof(int));
    int*    col    = (int*)alloc((size_t)E2 * sizeof(int));
    float*  dinv   = (float*)alloc(N_NODES * sizeof(float));
    float*  wsd    = (float*)alloc(64 * 8 * sizeof(float));
    unsigned short* xw1b = (unsigned short*)alloc((size_t)N_NODES * HID * sizeof(unsigned short));
    float*  h1     = (float*)alloc((size_t)N_NODES * HID * sizeof(float));
    float*  a_s    = (float*)alloc((size_t)N_NODES * HEADS * sizeof(float));
    float*  a_d    = (float*)alloc((size_t)N_NODES * HEADS * sizeof(float));
    unsigned short* xw2b = (unsigned short*)alloc((size_t)N_NODES * HH * sizeof(unsigned short));
    float2* xw3    = (float2*)alloc((size_t)N_NODES * sizeof(float2));

    const int gE = (E2 + 255) / 256;
    hipMemsetAsync(cnt, 0, N_NODES * sizeof(int), stream);
    k_hist<<<gE, 256, 0, stream>>>(ei, cnt);
    k_scan1<<<NSB, 256, 0, stream>>>(cnt, bsum);
    k_scan2<<<1, 128, 0, stream>>>(bsum);
    k_scan3<<<NSB, 256, 0, stream>>>(cnt, bsum, rowptr, dinv);
    hipMemsetAsync(cnt, 0, N_NODES * sizeof(int), stream);
    k_fill<<<gE, 256, 0, stream>>>(ei, rowptr, cnt, col);
    k_prews<<<8, 64, 0, stream>>>(W2, att_src, att_dst, wsd);

    k_gemm1<<<N_NODES / 32, 256, 0, stream>>>(x, W1, dinv, xw1b);
    k_agg1<<<(N_NODES + 3) / 4, 256, 0, stream>>>(rowptr, col, xw1b, dinv, b1, h1);
    k_gemm2<<<N_NODES / 32, 256, 0, stream>>>(h1, W2, wsd, xw2b, a_s, a_d);
    k_agg2<<<(N_NODES + 3) / 4, 256, 0, stream>>>(rowptr, col, xw2b, a_s, a_d, b2, W3, dinv, xw3);
    k_agg3<<<(N_NODES + 255) / 256, 256, 0, stream>>>(rowptr, col, xw3, dinv, b3, out);
}

// Round 6
// 603.088 us; speedup vs baseline: 1.0379x; 1.0379x over previous
//
#include <hip/hip_runtime.h>
#include <math.h>

// Problem constants (from reference)
#define N_NODES 100000
#define N_EDGES 1600000
#define E2      (N_NODES + N_EDGES)   // edges incl. self-loops = 1,700,000
#define IN_C    128
#define HID     64
#define HEADS   4
#define HH      256                    // HEADS*HID
#define OUT_C   2
#define NEG_SLOPE 0.2f

#define SB   1024                      // elements per scan block
#define NSB  ((N_NODES + SB - 1) / SB) // 98

__device__ __forceinline__ float bf2f(unsigned short u) {
    return __uint_as_float(((unsigned)u) << 16);
}
__device__ __forceinline__ unsigned short f2bf(float f) {
    unsigned u = __float_as_uint(f);
    u += 0x7fffu + ((u >> 16) & 1u);   // RNE
    return (unsigned short)(u >> 16);
}

// ---------------- CSR build ----------------

__global__ void k_hist(const int* __restrict__ ei, int* __restrict__ cnt) {
    int i = blockIdx.x * 256 + threadIdx.x;
    if (i >= E2) return;
    int d = (i < N_EDGES) ? ei[N_EDGES + i] : (i - N_EDGES);
    atomicAdd(&cnt[d], 1);
}

// scan1: per-block sums of cnt -> bsum[NSB]; extra 8 blocks do prews.
// wsd[k][o<4] = sum_c W2[k][o*64+c]*att_src[o*64+c]; o>=4 -> att_dst
__global__ __launch_bounds__(256) void k_scan1(const int* __restrict__ cnt,
        int* __restrict__ bsum, const float* __restrict__ W2,
        const float* __restrict__ att_src, const float* __restrict__ att_dst,
        float* __restrict__ wsd) {
    int b = blockIdx.x, t = threadIdx.x;
    if (b >= NSB) {                      // prews tail blocks
        if (t < 64) {
            int g = (b - NSB) * 64 + t;  // 0..511
            int k = g >> 3, o = g & 7;
            int h = o & 3;
            const float* att = (o < 4) ? att_src : att_dst;
            float acc = 0.f;
            const float* wrow = W2 + (size_t)k * HH + h * 64;
            const float* arow = att + h * 64;
            for (int c = 0; c < 64; ++c) acc = fmaf(wrow[c], arow[c], acc);
            wsd[k * 8 + o] = acc;
        }
        return;
    }
    int i = b * SB + t * 4;
    int s = 0;
    if (i + 3 < N_NODES) {
        int4 v = *(const int4*)(cnt + i);
        s = (v.x + v.y) + (v.z + v.w);
    } else {
        for (int k = 0; k < 4; ++k) if (i + k < N_NODES) s += cnt[i + k];
    }
#pragma unroll
    for (int off = 1; off < 64; off <<= 1) s += __shfl_xor(s, off);
    __shared__ int wsum[4];
    int lane = t & 63, wv = t >> 6;
    if (lane == 0) wsum[wv] = s;
    __syncthreads();
    if (t == 0) bsum[b] = (wsum[0] + wsum[1]) + (wsum[2] + wsum[3]);
}

// scan3: block b computes prefix over bsum[0..b) itself, scans its chunk,
// writes rowptr + dinv, and zeroes cur for k_fill.
__global__ __launch_bounds__(256) void k_scan3(const int* __restrict__ cnt,
        const int* __restrict__ bsum, int* __restrict__ rowptr,
        float* __restrict__ dinv, int* __restrict__ cur) {
    int b = blockIdx.x, t = threadIdx.x;
    int lane = t & 63, wv = t >> 6;
    // prefix of raw block sums: pre = sum_{i<b} bsum[i]
    __shared__ int wred[4];
    {
        int v = (t < b) ? bsum[t] : 0;   // b <= 98 <= 256
#pragma unroll
        for (int off = 1; off < 64; off <<= 1) v += __shfl_xor(v, off);
        if (lane == 0) wred[wv] = v;
    }
    __syncthreads();
    int pre = (wred[0] + wred[1]) + (wred[2] + wred[3]);
    __syncthreads();

    int i = b * SB + t * 4;
    int c0 = 0, c1 = 0, c2 = 0, c3 = 0;
    if (i + 3 < N_NODES) {
        int4 v = *(const int4*)(cnt + i);
        c0 = v.x; c1 = v.y; c2 = v.z; c3 = v.w;
    } else if (i < N_NODES) {
        c0 = cnt[i];
        if (i + 1 < N_NODES) c1 = cnt[i + 1];
        if (i + 2 < N_NODES) c2 = cnt[i + 2];
    }
    int s = (c0 + c1) + (c2 + c3);
    int inc = s;
#pragma unroll
    for (int off = 1; off < 64; off <<= 1) {
        int u = __shfl_up(inc, off);
        if (lane >= off) inc += u;
    }
    __shared__ int wtot[4];
    if (lane == 63) wtot[wv] = inc;
    __syncthreads();
    int base = pre + (inc - s);
    for (int w = 0; w < wv; ++w) base += wtot[w];
    if (i < N_NODES)     { rowptr[i]     = base;               dinv[i]     = rsqrtf((float)c0); }
    if (i + 1 < N_NODES) { rowptr[i + 1] = base + c0;           dinv[i + 1] = rsqrtf((float)c1); }
    if (i + 2 < N_NODES) { rowptr[i + 2] = base + c0 + c1;      dinv[i + 2] = rsqrtf((float)c2); }
    if (i + 3 < N_NODES) { rowptr[i + 3] = base + c0 + c1 + c2; dinv[i + 3] = rsqrtf((float)c3); }
    // zero cur for k_fill
    if (i + 3 < N_NODES) {
        *(int4*)(cur + i) = make_int4(0, 0, 0, 0);
    } else {
        for (int k = 0; k < 4; ++k) if (i + k < N_NODES) cur[i + k] = 0;
    }
    if (b == 0 && t == 0) rowptr[N_NODES] = E2;
}

__global__ void k_fill(const int* __restrict__ ei, const int* __restrict__ rowptr,
                       int* __restrict__ cur, int* __restrict__ col) {
    int i = blockIdx.x * 256 + threadIdx.x;
    if (i >= E2) return;
    int s, d;
    if (i < N_EDGES) { s = ei[i]; d = ei[N_EDGES + i]; }
    else             { s = d = i - N_EDGES; }
    int pos = rowptr[d] + atomicAdd(&cur[d], 1);
    col[pos] = s;
}

// ---------------- GEMM1: xw1b = bf16((x @ W1) * dinv[row])  [N,64] ----------
__global__ __launch_bounds__(256) void k_gemm1(const float* __restrict__ x,
        const float* __restrict__ W1, const float* __restrict__ dinv,
        unsigned short* __restrict__ xw1b) {
    __shared__ float xs[32 * IN_C];  // 16 KB
    int t = threadIdx.x;
    int r0 = blockIdx.x * 32;        // grid = N/32, exact
    const float4* xg = (const float4*)(x + (size_t)r0 * IN_C);
    float4* xs4 = (float4*)xs;
#pragma unroll
    for (int i = 0; i < 4; ++i) xs4[i * 256 + t] = xg[i * 256 + t];
    int lane = t & 63, wv = t >> 6;
    float w[IN_C];
#pragma unroll
    for (int k = 0; k < IN_C; ++k) w[k] = W1[k * HID + lane];
    __syncthreads();
    for (int j0 = 0; j0 < 8; j0 += 2) {
        int ja = wv * 8 + j0, jb = ja + 1;
        const float4* xa = (const float4*)(xs + ja * IN_C);
        const float4* xb = (const float4*)(xs + jb * IN_C);
        float aA = 0.f, aB = 0.f;
#pragma unroll
        for (int kk = 0; kk < 32; ++kk) {
            float4 va = xa[kk], vb = xb[kk];
            aA = fmaf(va.x, w[4 * kk + 0], aA);
            aA = fmaf(va.y, w[4 * kk + 1], aA);
            aA = fmaf(va.z, w[4 * kk + 2], aA);
            aA = fmaf(va.w, w[4 * kk + 3], aA);
            aB = fmaf(vb.x, w[4 * kk + 0], aB);
            aB = fmaf(vb.y, w[4 * kk + 1], aB);
            aB = fmaf(vb.z, w[4 * kk + 2], aB);
            aB = fmaf(vb.w, w[4 * kk + 3], aB);
        }
        int ra = r0 + ja, rb = r0 + jb;
        xw1b[(size_t)ra * HID + lane] = f2bf(aA * dinv[ra]);
        xw1b[(size_t)rb * HID + lane] = f2bf(aB * dinv[rb]);
    }
}

// ---------------- GCN1 aggregate: h1 = relu(dinv[d]*sum_s xw1[s] + b1) ------
// wave per dst; 16 lanes per edge (ushort4 = 4 bf16 ch/lane), 4 edges/group.
__global__ __launch_bounds__(256) void k_agg1(const int* __restrict__ rowptr,
        const int* __restrict__ col, const unsigned short* __restrict__ xw1b,
        const float* __restrict__ dinv, const float* __restrict__ b1,
        float* __restrict__ h1) {
    int t = threadIdx.x;
    int lane = t & 63;
    int d = blockIdx.x * 4 + (t >> 6);
    if (d >= N_NODES) return;
    int start = rowptr[d], end = rowptr[d + 1];
    int sub = lane >> 4;       // which of 4 edges in a group
    int cpos = lane & 15;      // channel quad (4 bf16)
    float4 acc = make_float4(0.f, 0.f, 0.f, 0.f);
    for (int base = start; base < end; base += 64) {
        int cnt = min(64, end - base);
        int sl = (base + lane < end) ? col[base + lane] : 0;
#pragma unroll 4
        for (int j = 0; j < cnt; j += 4) {
            int idx = j + sub;
            int sj = __shfl(sl, idx);
            if (idx < cnt) {
                ushort4 v = ((const ushort4*)(xw1b + (size_t)sj * HID))[cpos];
                acc.x += bf2f(v.x); acc.y += bf2f(v.y);
                acc.z += bf2f(v.z); acc.w += bf2f(v.w);
            }
        }
    }
    acc.x += __shfl_xor(acc.x, 16); acc.y += __shfl_xor(acc.y, 16);
    acc.z += __shfl_xor(acc.z, 16); acc.w += __shfl_xor(acc.w, 16);
    acc.x += __shfl_xor(acc.x, 32); acc.y += __shfl_xor(acc.y, 32);
    acc.z += __shfl_xor(acc.z, 32); acc.w += __shfl_xor(acc.w, 32);
    if (lane < 16) {
        float di = dinv[d];
        float4 b = ((const float4*)b1)[lane];
        float4 o;
        o.x = fmaf(acc.x, di, b.x); o.x = o.x > 0.f ? o.x : 0.f;
        o.y = fmaf(acc.y, di, b.y); o.y = o.y > 0.f ? o.y : 0.f;
        o.z = fmaf(acc.z, di, b.z); o.z = o.z > 0.f ? o.z : 0.f;
        o.w = fmaf(acc.w, di, b.w); o.w = o.w > 0.f ? o.w : 0.f;
        ((float4*)(h1 + (size_t)d * HID))[lane] = o;
    }
}

// ---------------- GEMM2: xw2b = bf16(h1 @ W2) [n][c*4+h], a_s, a_d ----------
__global__ __launch_bounds__(256) void k_gemm2(const float* __restrict__ h1,
        const float* __restrict__ W2, const float* __restrict__ wsd,
        unsigned short* __restrict__ xw2b, float* __restrict__ a_s,
        float* __restrict__ a_d) {
    __shared__ float hs[32 * HID];   // 8 KB
    __shared__ float ws[512];        // 2 KB
    int t = threadIdx.x;
    int r0 = blockIdx.x * 32;        // grid = N/32, exact
    const float4* hg = (const float4*)(h1 + (size_t)r0 * HID);
    float4* hs4 = (float4*)hs;
#pragma unroll
    for (int i = 0; i < 2; ++i) hs4[i * 256 + t] = hg[i * 256 + t];
    ((float2*)ws)[t] = ((const float2*)wsd)[t];
    float w[HID];
#pragma unroll
    for (int k = 0; k < HID; ++k) w[k] = W2[k * HH + t];
    __syncthreads();
    int lane = t & 63, h = t >> 6;
    for (int j = 0; j < 32; j += 2) {
        const float4* ha = (const float4*)(hs + j * HID);
        const float4* hb = (const float4*)(hs + (j + 1) * HID);
        float aA = 0.f, aB = 0.f;
#pragma unroll
        for (int kk = 0; kk < 16; ++kk) {
            float4 va = ha[kk], vb = hb[kk];
            aA = fmaf(va.x, w[4 * kk + 0], aA);
            aA = fmaf(va.y, w[4 * kk + 1], aA);
            aA = fmaf(va.z, w[4 * kk + 2], aA);
            aA = fmaf(va.w, w[4 * kk + 3], aA);
            aB = fmaf(vb.x, w[4 * kk + 0], aB);
            aB = fmaf(vb.y, w[4 * kk + 1], aB);
            aB = fmaf(vb.z, w[4 * kk + 2], aB);
            aB = fmaf(vb.w, w[4 * kk + 3], aB);
        }
        xw2b[(size_t)(r0 + j) * HH + lane * 4 + h] = f2bf(aA);
        xw2b[(size_t)(r0 + j + 1) * HH + lane * 4 + h] = f2bf(aB);
    }
    {
        int j = t >> 3, o = t & 7;
        const float* hrow = hs + j * HID;
        float acc = 0.f;
#pragma unroll
        for (int k = 0; k < 64; ++k) {
            int ke = (k + j) & 63;
            acc = fmaf(hrow[ke], ws[ke * 8 + o], acc);
        }
        int r = r0 + j;
        if (o < 4) a_s[r * 4 + o] = acc;
        else       a_d[r * 4 + (o - 4)] = acc;
    }
}

// ---------------- GAT aggregate + ELU + fused GEMM3 -------------------------
// unroll 4: unroll 8 raised VGPR 32->48, occupancy 79->48%, dur +14% (round 5)
__global__ __launch_bounds__(256) void k_agg2(const int* __restrict__ rowptr,
        const int* __restrict__ col, const unsigned short* __restrict__ xw2b,
        const float* __restrict__ a_s, const float* __restrict__ a_d,
        const float* __restrict__ b2, const float* __restrict__ W3,
        const float* __restrict__ dinv, float2* __restrict__ xw3) {
    __shared__ int   ss[4][64];      // 1 KB
    __shared__ float sp[4][64][4];   // 4 KB
    int t = threadIdx.x;
    int lane = t & 63, wv = t >> 6;
    int d = blockIdx.x * 4 + wv;
    if (d >= N_NODES) return;
    const float4* as4 = (const float4*)a_s;
    float4 adv = ((const float4*)a_d)[d];
    int start = rowptr[d], end = rowptr[d + 1];

    float den0 = 0.f, den1 = 0.f, den2 = 0.f, den3 = 0.f;
    float acc0 = 0.f, acc1 = 0.f, acc2 = 0.f, acc3 = 0.f;
    const ushort4* xw24 = (const ushort4*)xw2b;      // row = 64 ushort4
    for (int base = start; base < end; base += 64) {
        int cnt = min(64, end - base);
        float p0 = 0.f, p1 = 0.f, p2 = 0.f, p3 = 0.f;
        int s = 0;
        if (lane < cnt) {
            s = col[base + lane];
            float4 av = as4[s];
            float v;
            v = av.x + adv.x; v = v > 0.f ? v : NEG_SLOPE * v; p0 = __expf(v);
            v = av.y + adv.y; v = v > 0.f ? v : NEG_SLOPE * v; p1 = __expf(v);
            v = av.z + adv.z; v = v > 0.f ? v : NEG_SLOPE * v; p2 = __expf(v);
            v = av.w + adv.w; v = v > 0.f ? v : NEG_SLOPE * v; p3 = __expf(v);
            den0 += p0; den1 += p1; den2 += p2; den3 += p3;
        }
        ss[wv][lane] = s;                                  // wave-private LDS
        ((float4*)sp[wv])[lane] = make_float4(p0, p1, p2, p3);
#pragma unroll 4
        for (int j = 0; j < cnt; ++j) {
            int sj = ss[wv][j];                            // broadcast read
            float4 pj = ((const float4*)sp[wv])[j];        // broadcast read
            ushort4 xv = xw24[(size_t)sj * 64 + lane];     // 8B/lane coalesced
            acc0 = fmaf(pj.x, bf2f(xv.x), acc0);
            acc1 = fmaf(pj.y, bf2f(xv.y), acc1);
            acc2 = fmaf(pj.z, bf2f(xv.z), acc2);
            acc3 = fmaf(pj.w, bf2f(xv.w), acc3);
        }
    }
#pragma unroll
    for (int mk = 1; mk < 64; mk <<= 1) {
        den0 += __shfl_xor(den0, mk);
        den1 += __shfl_xor(den1, mk);
        den2 += __shfl_xor(den2, mk);
        den3 += __shfl_xor(den3, mk);
    }

    float o0 = acc0 / (den0 + 1e-16f) + b2[lane];
    float o1 = acc1 / (den1 + 1e-16f) + b2[64 + lane];
    float o2 = acc2 / (den2 + 1e-16f) + b2[128 + lane];
    float o3 = acc3 / (den3 + 1e-16f) + b2[192 + lane];
    o0 = o0 > 0.f ? o0 : expm1f(o0);
    o1 = o1 > 0.f ? o1 : expm1f(o1);
    o2 = o2 > 0.f ? o2 : expm1f(o2);
    o3 = o3 > 0.f ? o3 : expm1f(o3);
    const float2* w32 = (const float2*)W3;     // W3[256][2]
    float2 w0 = w32[lane], w1 = w32[64 + lane];
    float2 w2 = w32[128 + lane], w3 = w32[192 + lane];
    float px = o0 * w0.x + o1 * w1.x + o2 * w2.x + o3 * w3.x;
    float py = o0 * w0.y + o1 * w1.y + o2 * w2.y + o3 * w3.y;
#pragma unroll
    for (int mk = 1; mk < 64; mk <<= 1) {
        px += __shfl_xor(px, mk);
        py += __shfl_xor(py, mk);
    }
    if (lane == 0) {
        float di = dinv[d];
        xw3[d] = make_float2(px * di, py * di);
    }
}

// ---------------- GCN2 aggregate: out = dinv[d]*sum_s xw3[s] + b3 -----------
__global__ void k_agg3(const int* __restrict__ rowptr, const int* __restrict__ col,
        const float2* __restrict__ xw3, const float* __restrict__ dinv,
        const float* __restrict__ b3, float* __restrict__ out) {
    int d = blockIdx.x * 256 + threadIdx.x;
    if (d >= N_NODES) return;
    int e = rowptr[d], end = rowptr[d + 1];
    float a0 = 0.f, a1 = 0.f;
    for (; e < end; ++e) {
        float2 v = xw3[col[e]];
        a0 += v.x; a1 += v.y;
    }
    float di = dinv[d];
    out[d * 2 + 0] = fmaf(a0, di, b3[0]);
    out[d * 2 + 1] = fmaf(a1, di, b3[1]);
}

// ---------------- launch ----------------

extern "C" void kernel_launch(void* const* d_in, const int* in_sizes, int n_in,
                              void* d_out, int out_size, void* d_ws, size_t ws_size,
                              hipStream_t stream) {
    const float* x       = (const float*)d_in[0];
    const int*   ei      = (const int*)d_in[1];
    const float* W1      = (const float*)d_in[2];
    const float* b1      = (const float*)d_in[3];
    const float* W2      = (const float*)d_in[4];
    const float* att_src = (const float*)d_in[5];
    const float* att_dst = (const float*)d_in[6];
    const float* b2      = (const float*)d_in[7];
    const float* W3      = (const float*)d_in[8];
    const float* b3      = (const float*)d_in[9];
    float* out = (float*)d_out;
    (void)in_sizes; (void)n_in; (void)out_size; (void)ws_size;

    char* ws = (char*)d_ws;
    size_t off = 0;
    auto alloc = [&](size_t bytes) -> void* {
        void* p = ws + off;
        off = (off + bytes + 255) & ~(size_t)255;
        return p;
    };
    int*    rowptr = (int*)alloc((N_NODES + 1) * sizeof(int));
    int*    cnt    = (int*)alloc(N_NODES * sizeof(int));
    int*    cur    = (int*)alloc(N_NODES * sizeof(int));
    int*    bsum   = (int*)alloc(NSB * sizeof(int));
    int*    col    = (int*)alloc((size_t)E2 * sizeof(int));
    float*  dinv   = (float*)alloc(N_NODES * sizeof(float));
    float*  wsd    = (float*)alloc(64 * 8 * sizeof(float));
    unsigned short* xw1b = (unsigned short*)alloc((size_t)N_NODES * HID * sizeof(unsigned short));
    float*  h1     = (float*)alloc((size_t)N_NODES * HID * sizeof(float));
    float*  a_s    = (float*)alloc((size_t)N_NODES * HEADS * sizeof(float));
    float*  a_d    = (float*)alloc((size_t)N_NODES * HEADS * sizeof(float));
    unsigned short* xw2b = (unsigned short*)alloc((size_t)N_NODES * HH * sizeof(unsigned short));
    float2* xw3    = (float2*)alloc((size_t)N_NODES * sizeof(float2));

    const int gE = (E2 + 255) / 256;
    hipMemsetAsync(cnt, 0, N_NODES * sizeof(int), stream);
    k_hist<<<gE, 256, 0, stream>>>(ei, cnt);
    k_scan1<<<NSB + 8, 256, 0, stream>>>(cnt, bsum, W2, att_src, att_dst, wsd);
    k_scan3<<<NSB, 256, 0, stream>>>(cnt, bsum, rowptr, dinv, cur);
    k_fill<<<gE, 256, 0, stream>>>(ei, rowptr, cur, col);

    k_gemm1<<<N_NODES / 32, 256, 0, stream>>>(x, W1, dinv, xw1b);
    k_agg1<<<(N_NODES + 3) / 4, 256, 0, stream>>>(rowptr, col, xw1b, dinv, b1, h1);
    k_gemm2<<<N_NODES / 32, 256, 0, stream>>>(h1, W2, wsd, xw2b, a_s, a_d);
    k_agg2<<<(N_NODES + 3) / 4, 256, 0, stream>>>(rowptr, col, xw2b, a_s, a_d, b2, W3, dinv, xw3);
    k_agg3<<<(N_NODES + 255) / 256, 256, 0, stream>>>(rowptr, col, xw3, dinv, b3, out);
}

// Round 7
// 591.641 us; speedup vs baseline: 1.0580x; 1.0193x over previous
//
#include <hip/hip_runtime.h>
#include <math.h>

// Problem constants (from reference)
#define N_NODES 100000
#define N_EDGES 1600000
#define E2      (N_NODES + N_EDGES)   // edges incl. self-loops = 1,700,000
#define IN_C    128
#define HID     64
#define HEADS   4
#define HH      256                    // HEADS*HID
#define OUT_C   2
#define NEG_SLOPE 0.2f

#define SB   1024                      // elements per scan block
#define NSB  ((N_NODES + SB - 1) / SB) // 98

__device__ __forceinline__ float bf2f(unsigned short u) {
    return __uint_as_float(((unsigned)u) << 16);
}
__device__ __forceinline__ unsigned short f2bf(float f) {
    unsigned u = __float_as_uint(f);
    u += 0x7fffu + ((u >> 16) & 1u);   // RNE
    return (unsigned short)(u >> 16);
}

// ---------------- CSR build ----------------
// cnt[] counts REAL edges only; degree = cnt+1 (self-loop). Self-loop is
// pre-placed at slot 0 of each segment by k_scan3 (sequential-ish sweep),
// real edges fill slots 1.. via atomics. Cuts 200k device-scope atomics.

__global__ void k_hist(const int* __restrict__ dst, int* __restrict__ cnt) {
    int i = blockIdx.x * 256 + threadIdx.x;
    if (i >= N_EDGES) return;
    atomicAdd(&cnt[dst[i]], 1);
}

// scan1: per-block sums of (cnt+1) -> bsum[NSB]; extra 8 blocks do prews.
// wsd[k][o<4] = sum_c W2[k][o*64+c]*att_src[o*64+c]; o>=4 -> att_dst
__global__ __launch_bounds__(256) void k_scan1(const int* __restrict__ cnt,
        int* __restrict__ bsum, const float* __restrict__ W2,
        const float* __restrict__ att_src, const float* __restrict__ att_dst,
        float* __restrict__ wsd) {
    int b = blockIdx.x, t = threadIdx.x;
    if (b >= NSB) {                      // prews tail blocks
        if (t < 64) {
            int g = (b - NSB) * 64 + t;  // 0..511
            int k = g >> 3, o = g & 7;
            int h = o & 3;
            const float* att = (o < 4) ? att_src : att_dst;
            float acc = 0.f;
            const float* wrow = W2 + (size_t)k * HH + h * 64;
            const float* arow = att + h * 64;
            for (int c = 0; c < 64; ++c) acc = fmaf(wrow[c], arow[c], acc);
            wsd[k * 8 + o] = acc;
        }
        return;
    }
    int i = b * SB + t * 4;
    int s = 0;
    if (i + 3 < N_NODES) {
        int4 v = *(const int4*)(cnt + i);
        s = (v.x + v.y) + (v.z + v.w) + 4;       // +1 self-loop per node
    } else {
        for (int k = 0; k < 4; ++k) if (i + k < N_NODES) s += cnt[i + k] + 1;
    }
#pragma unroll
    for (int off = 1; off < 64; off <<= 1) s += __shfl_xor(s, off);
    __shared__ int wsum[4];
    int lane = t & 63, wv = t >> 6;
    if (lane == 0) wsum[wv] = s;
    __syncthreads();
    if (t == 0) bsum[b] = (wsum[0] + wsum[1]) + (wsum[2] + wsum[3]);
}

// scan3: block b computes prefix over bsum[0..b) itself, scans its chunk
// (deg = cnt+1), writes rowptr + dinv, zeroes cur, pre-places self-loops.
__global__ __launch_bounds__(256) void k_scan3(const int* __restrict__ cnt,
        const int* __restrict__ bsum, int* __restrict__ rowptr,
        float* __restrict__ dinv, int* __restrict__ cur, int* __restrict__ col) {
    int b = blockIdx.x, t = threadIdx.x;
    int lane = t & 63, wv = t >> 6;
    __shared__ int wred[4];
    {
        int v = (t < b) ? bsum[t] : 0;   // b <= 98 <= 256
#pragma unroll
        for (int off = 1; off < 64; off <<= 1) v += __shfl_xor(v, off);
        if (lane == 0) wred[wv] = v;
    }
    __syncthreads();
    int pre = (wred[0] + wred[1]) + (wred[2] + wred[3]);
    __syncthreads();

    int i = b * SB + t * 4;
    int c0 = 0, c1 = 0, c2 = 0, c3 = 0;
    if (i + 3 < N_NODES) {
        int4 v = *(const int4*)(cnt + i);
        c0 = v.x; c1 = v.y; c2 = v.z; c3 = v.w;
    } else if (i < N_NODES) {
        c0 = cnt[i];
        if (i + 1 < N_NODES) c1 = cnt[i + 1];
        if (i + 2 < N_NODES) c2 = cnt[i + 2];
    }
    int n0 = (i < N_NODES), n1 = (i + 1 < N_NODES),
        n2 = (i + 2 < N_NODES), n3 = (i + 3 < N_NODES);
    int d0 = c0 + n0, d1 = c1 + n1, d2 = c2 + n2, d3 = c3 + n3;  // degrees
    int s = (d0 + d1) + (d2 + d3);
    int inc = s;
#pragma unroll
    for (int off = 1; off < 64; off <<= 1) {
        int u = __shfl_up(inc, off);
        if (lane >= off) inc += u;
    }
    __shared__ int wtot[4];
    if (lane == 63) wtot[wv] = inc;
    __syncthreads();
    int base = pre + (inc - s);
    for (int w = 0; w < wv; ++w) base += wtot[w];
    if (n0) { rowptr[i]     = base;                dinv[i]     = rsqrtf((float)d0); col[base] = i; }
    if (n1) { rowptr[i + 1] = base + d0;           dinv[i + 1] = rsqrtf((float)d1); col[base + d0] = i + 1; }
    if (n2) { rowptr[i + 2] = base + d0 + d1;      dinv[i + 2] = rsqrtf((float)d2); col[base + d0 + d1] = i + 2; }
    if (n3) { rowptr[i + 3] = base + d0 + d1 + d2; dinv[i + 3] = rsqrtf((float)d3); col[base + d0 + d1 + d2] = i + 3; }
    // zero cur for k_fill
    if (n3) {
        *(int4*)(cur + i) = make_int4(0, 0, 0, 0);
    } else {
        for (int k = 0; k < 4; ++k) if (i + k < N_NODES) cur[i + k] = 0;
    }
    if (b == 0 && t == 0) rowptr[N_NODES] = E2;
}

__global__ void k_fill(const int* __restrict__ ei, const int* __restrict__ rowptr,
                       int* __restrict__ cur, int* __restrict__ col) {
    int i = blockIdx.x * 256 + threadIdx.x;
    if (i >= N_EDGES) return;
    int s = ei[i], d = ei[N_EDGES + i];
    int pos = rowptr[d] + 1 + atomicAdd(&cur[d], 1);   // slot 0 = self-loop
    col[pos] = s;
}

// ---------------- GEMM1: xw1b = bf16((x @ W1) * dinv[row])  [N,64] ----------
__global__ __launch_bounds__(256) void k_gemm1(const float* __restrict__ x,
        const float* __restrict__ W1, const float* __restrict__ dinv,
        unsigned short* __restrict__ xw1b) {
    __shared__ float xs[32 * IN_C];  // 16 KB
    int t = threadIdx.x;
    int r0 = blockIdx.x * 32;        // grid = N/32, exact
    const float4* xg = (const float4*)(x + (size_t)r0 * IN_C);
    float4* xs4 = (float4*)xs;
#pragma unroll
    for (int i = 0; i < 4; ++i) xs4[i * 256 + t] = xg[i * 256 + t];
    int lane = t & 63, wv = t >> 6;
    float w[IN_C];
#pragma unroll
    for (int k = 0; k < IN_C; ++k) w[k] = W1[k * HID + lane];
    __syncthreads();
    for (int j0 = 0; j0 < 8; j0 += 2) {
        int ja = wv * 8 + j0, jb = ja + 1;
        const float4* xa = (const float4*)(xs + ja * IN_C);
        const float4* xb = (const float4*)(xs + jb * IN_C);
        float aA = 0.f, aB = 0.f;
#pragma unroll
        for (int kk = 0; kk < 32; ++kk) {
            float4 va = xa[kk], vb = xb[kk];
            aA = fmaf(va.x, w[4 * kk + 0], aA);
            aA = fmaf(va.y, w[4 * kk + 1], aA);
            aA = fmaf(va.z, w[4 * kk + 2], aA);
            aA = fmaf(va.w, w[4 * kk + 3], aA);
            aB = fmaf(vb.x, w[4 * kk + 0], aB);
            aB = fmaf(vb.y, w[4 * kk + 1], aB);
            aB = fmaf(vb.z, w[4 * kk + 2], aB);
            aB = fmaf(vb.w, w[4 * kk + 3], aB);
        }
        int ra = r0 + ja, rb = r0 + jb;
        xw1b[(size_t)ra * HID + lane] = f2bf(aA * dinv[ra]);
        xw1b[(size_t)rb * HID + lane] = f2bf(aB * dinv[rb]);
    }
}

// ---------------- GCN1 aggregate: h1b = bf16(relu(dinv*sum + b1)) -----------
// wave per dst; 16 lanes per edge (ushort4 = 4 bf16 ch/lane), 4 edges/group,
// unroll 2 -> 8 gathers in flight (VGPR-guarded; round-5 cliff was at 48).
__global__ __launch_bounds__(256) void k_agg1(const int* __restrict__ rowptr,
        const int* __restrict__ col, const unsigned short* __restrict__ xw1b,
        const float* __restrict__ dinv, const float* __restrict__ b1,
        unsigned short* __restrict__ h1b) {
    int t = threadIdx.x;
    int lane = t & 63;
    int d = blockIdx.x * 4 + (t >> 6);
    if (d >= N_NODES) return;
    int start = rowptr[d], end = rowptr[d + 1];
    int sub = lane >> 4;       // which of 4 edges in a group
    int cpos = lane & 15;      // channel quad (4 bf16)
    float4 acc = make_float4(0.f, 0.f, 0.f, 0.f);
    for (int base = start; base < end; base += 64) {
        int cnt = min(64, end - base);
        int sl = (base + lane < end) ? col[base + lane] : 0;
#pragma unroll 2
        for (int j = 0; j < cnt; j += 4) {
            int idx = j + sub;
            int sj = __shfl(sl, idx);
            if (idx < cnt) {
                ushort4 v = ((const ushort4*)(xw1b + (size_t)sj * HID))[cpos];
                acc.x += bf2f(v.x); acc.y += bf2f(v.y);
                acc.z += bf2f(v.z); acc.w += bf2f(v.w);
            }
        }
    }
    acc.x += __shfl_xor(acc.x, 16); acc.y += __shfl_xor(acc.y, 16);
    acc.z += __shfl_xor(acc.z, 16); acc.w += __shfl_xor(acc.w, 16);
    acc.x += __shfl_xor(acc.x, 32); acc.y += __shfl_xor(acc.y, 32);
    acc.z += __shfl_xor(acc.z, 32); acc.w += __shfl_xor(acc.w, 32);
    if (lane < 16) {
        float di = dinv[d];
        float4 b = ((const float4*)b1)[lane];
        float ox = fmaf(acc.x, di, b.x); ox = ox > 0.f ? ox : 0.f;
        float oy = fmaf(acc.y, di, b.y); oy = oy > 0.f ? oy : 0.f;
        float oz = fmaf(acc.z, di, b.z); oz = oz > 0.f ? oz : 0.f;
        float ow = fmaf(acc.w, di, b.w); ow = ow > 0.f ? ow : 0.f;
        ushort4 o = make_ushort4(f2bf(ox), f2bf(oy), f2bf(oz), f2bf(ow));
        ((ushort4*)(h1b + (size_t)d * HID))[lane] = o;
    }
}

// ---------------- GEMM2: xw2b = bf16(h1 @ W2) [n][c*4+h], a_s, a_d ----------
__global__ __launch_bounds__(256) void k_gemm2(const unsigned short* __restrict__ h1b,
        const float* __restrict__ W2, const float* __restrict__ wsd,
        unsigned short* __restrict__ xw2b, float* __restrict__ a_s,
        float* __restrict__ a_d) {
    __shared__ float hs[32 * HID];   // 8 KB (fp32, converted at stage-in)
    __shared__ float ws[512];        // 2 KB
    int t = threadIdx.x;
    int r0 = blockIdx.x * 32;        // grid = N/32, exact
    const ushort4* hg = (const ushort4*)(h1b + (size_t)r0 * HID);  // 512 total
#pragma unroll
    for (int i = 0; i < 2; ++i) {
        ushort4 v = hg[i * 256 + t];
        ((float4*)hs)[i * 256 + t] =
            make_float4(bf2f(v.x), bf2f(v.y), bf2f(v.z), bf2f(v.w));
    }
    ((float2*)ws)[t] = ((const float2*)wsd)[t];
    float w[HID];
#pragma unroll
    for (int k = 0; k < HID; ++k) w[k] = W2[k * HH + t];
    __syncthreads();
    int lane = t & 63, h = t >> 6;
    for (int j = 0; j < 32; j += 2) {
        const float4* ha = (const float4*)(hs + j * HID);
        const float4* hb = (const float4*)(hs + (j + 1) * HID);
        float aA = 0.f, aB = 0.f;
#pragma unroll
        for (int kk = 0; kk < 16; ++kk) {
            float4 va = ha[kk], vb = hb[kk];
            aA = fmaf(va.x, w[4 * kk + 0], aA);
            aA = fmaf(va.y, w[4 * kk + 1], aA);
            aA = fmaf(va.z, w[4 * kk + 2], aA);
            aA = fmaf(va.w, w[4 * kk + 3], aA);
            aB = fmaf(vb.x, w[4 * kk + 0], aB);
            aB = fmaf(vb.y, w[4 * kk + 1], aB);
            aB = fmaf(vb.z, w[4 * kk + 2], aB);
            aB = fmaf(vb.w, w[4 * kk + 3], aB);
        }
        xw2b[(size_t)(r0 + j) * HH + lane * 4 + h] = f2bf(aA);
        xw2b[(size_t)(r0 + j + 1) * HH + lane * 4 + h] = f2bf(aB);
    }
    {
        int j = t >> 3, o = t & 7;
        const float* hrow = hs + j * HID;
        float acc = 0.f;
#pragma unroll
        for (int k = 0; k < 64; ++k) {
            int ke = (k + j) & 63;
            acc = fmaf(hrow[ke], ws[ke * 8 + o], acc);
        }
        int r = r0 + j;
        if (o < 4) a_s[r * 4 + o] = acc;
        else       a_d[r * 4 + (o - 4)] = acc;
    }
}

// ---------------- GAT aggregate + ELU + fused GEMM3 -------------------------
// unroll 4: unroll 8 raised VGPR 32->48, occupancy 79->48%, dur +14% (round 5)
__global__ __launch_bounds__(256) void k_agg2(const int* __restrict__ rowptr,
        const int* __restrict__ col, const unsigned short* __restrict__ xw2b,
        const float* __restrict__ a_s, const float* __restrict__ a_d,
        const float* __restrict__ b2, const float* __restrict__ W3,
        const float* __restrict__ dinv, float2* __restrict__ xw3) {
    __shared__ int   ss[4][64];      // 1 KB
    __shared__ float sp[4][64][4];   // 4 KB
    int t = threadIdx.x;
    int lane = t & 63, wv = t >> 6;
    int d = blockIdx.x * 4 + wv;
    if (d >= N_NODES) return;
    const float4* as4 = (const float4*)a_s;
    float4 adv = ((const float4*)a_d)[d];
    int start = rowptr[d], end = rowptr[d + 1];

    float den0 = 0.f, den1 = 0.f, den2 = 0.f, den3 = 0.f;
    float acc0 = 0.f, acc1 = 0.f, acc2 = 0.f, acc3 = 0.f;
    const ushort4* xw24 = (const ushort4*)xw2b;      // row = 64 ushort4
    for (int base = start; base < end; base += 64) {
        int cnt = min(64, end - base);
        float p0 = 0.f, p1 = 0.f, p2 = 0.f, p3 = 0.f;
        int s = 0;
        if (lane < cnt) {
            s = col[base + lane];
            float4 av = as4[s];
            float v;
            v = av.x + adv.x; v = v > 0.f ? v : NEG_SLOPE * v; p0 = __expf(v);
            v = av.y + adv.y; v = v > 0.f ? v : NEG_SLOPE * v; p1 = __expf(v);
            v = av.z + adv.z; v = v > 0.f ? v : NEG_SLOPE * v; p2 = __expf(v);
            v = av.w + adv.w; v = v > 0.f ? v : NEG_SLOPE * v; p3 = __expf(v);
            den0 += p0; den1 += p1; den2 += p2; den3 += p3;
        }
        ss[wv][lane] = s;                                  // wave-private LDS
        ((float4*)sp[wv])[lane] = make_float4(p0, p1, p2, p3);
#pragma unroll 4
        for (int j = 0; j < cnt; ++j) {
            int sj = ss[wv][j];                            // broadcast read
            float4 pj = ((const float4*)sp[wv])[j];        // broadcast read
            ushort4 xv = xw24[(size_t)sj * 64 + lane];     // 8B/lane coalesced
            acc0 = fmaf(pj.x, bf2f(xv.x), acc0);
            acc1 = fmaf(pj.y, bf2f(xv.y), acc1);
            acc2 = fmaf(pj.z, bf2f(xv.z), acc2);
            acc3 = fmaf(pj.w, bf2f(xv.w), acc3);
        }
    }
#pragma unroll
    for (int mk = 1; mk < 64; mk <<= 1) {
        den0 += __shfl_xor(den0, mk);
        den1 += __shfl_xor(den1, mk);
        den2 += __shfl_xor(den2, mk);
        den3 += __shfl_xor(den3, mk);
    }

    float o0 = acc0 / (den0 + 1e-16f) + b2[lane];
    float o1 = acc1 / (den1 + 1e-16f) + b2[64 + lane];
    float o2 = acc2 / (den2 + 1e-16f) + b2[128 + lane];
    float o3 = acc3 / (den3 + 1e-16f) + b2[192 + lane];
    o0 = o0 > 0.f ? o0 : expm1f(o0);
    o1 = o1 > 0.f ? o1 : expm1f(o1);
    o2 = o2 > 0.f ? o2 : expm1f(o2);
    o3 = o3 > 0.f ? o3 : expm1f(o3);
    const float2* w32 = (const float2*)W3;     // W3[256][2]
    float2 w0 = w32[lane], w1 = w32[64 + lane];
    float2 w2 = w32[128 + lane], w3 = w32[192 + lane];
    float px = o0 * w0.x + o1 * w1.x + o2 * w2.x + o3 * w3.x;
    float py = o0 * w0.y + o1 * w1.y + o2 * w2.y + o3 * w3.y;
#pragma unroll
    for (int mk = 1; mk < 64; mk <<= 1) {
        px += __shfl_xor(px, mk);
        py += __shfl_xor(py, mk);
    }
    if (lane == 0) {
        float di = dinv[d];
        xw3[d] = make_float2(px * di, py * di);
    }
}

// ---------------- GCN2 aggregate: out = dinv[d]*sum_s xw3[s] + b3 -----------
__global__ void k_agg3(const int* __restrict__ rowptr, const int* __restrict__ col,
        const float2* __restrict__ xw3, const float* __restrict__ dinv,
        const float* __restrict__ b3, float* __restrict__ out) {
    int d = blockIdx.x * 256 + threadIdx.x;
    if (d >= N_NODES) return;
    int e = rowptr[d], end = rowptr[d + 1];
    float a0 = 0.f, a1 = 0.f;
    for (; e < end; ++e) {
        float2 v = xw3[col[e]];
        a0 += v.x; a1 += v.y;
    }
    float di = dinv[d];
    out[d * 2 + 0] = fmaf(a0, di, b3[0]);
    out[d * 2 + 1] = fmaf(a1, di, b3[1]);
}

// ---------------- launch ----------------

extern "C" void kernel_launch(void* const* d_in, const int* in_sizes, int n_in,
                              void* d_out, int out_size, void* d_ws, size_t ws_size,
                              hipStream_t stream) {
    const float* x       = (const float*)d_in[0];
    const int*   ei      = (const int*)d_in[1];
    const float* W1      = (const float*)d_in[2];
    const float* b1      = (const float*)d_in[3];
    const float* W2      = (const float*)d_in[4];
    const float* att_src = (const float*)d_in[5];
    const float* att_dst = (const float*)d_in[6];
    const float* b2      = (const float*)d_in[7];
    const float* W3      = (const float*)d_in[8];
    const float* b3      = (const float*)d_in[9];
    float* out = (float*)d_out;
    (void)in_sizes; (void)n_in; (void)out_size; (void)ws_size;

    char* ws = (char*)d_ws;
    size_t off = 0;
    auto alloc = [&](size_t bytes) -> void* {
        void* p = ws + off;
        off = (off + bytes + 255) & ~(size_t)255;
        return p;
    };
    int*    rowptr = (int*)alloc((N_NODES + 1) * sizeof(int));
    int*    cnt    = (int*)alloc(N_NODES * sizeof(int));
    int*    cur    = (int*)alloc(N_NODES * sizeof(int));
    int*    bsum   = (int*)alloc(NSB * sizeof(int));
    int*    col    = (int*)alloc((size_t)E2 * sizeof(int));
    float*  dinv   = (float*)alloc(N_NODES * sizeof(float));
    float*  wsd    = (float*)alloc(64 * 8 * sizeof(float));
    unsigned short* xw1b = (unsigned short*)alloc((size_t)N_NODES * HID * sizeof(unsigned short));
    unsigned short* h1b  = (unsigned short*)alloc((size_t)N_NODES * HID * sizeof(unsigned short));
    float*  a_s    = (float*)alloc((size_t)N_NODES * HEADS * sizeof(float));
    float*  a_d    = (float*)alloc((size_t)N_NODES * HEADS * sizeof(float));
    unsigned short* xw2b = (unsigned short*)alloc((size_t)N_NODES * HH * sizeof(unsigned short));
    float2* xw3    = (float2*)alloc((size_t)N_NODES * sizeof(float2));

    const int gE = (N_EDGES + 255) / 256;
    hipMemsetAsync(cnt, 0, N_NODES * sizeof(int), stream);
    k_hist<<<gE, 256, 0, stream>>>(ei + N_EDGES, cnt);
    k_scan1<<<NSB + 8, 256, 0, stream>>>(cnt, bsum, W2, att_src, att_dst, wsd);
    k_scan3<<<NSB, 256, 0, stream>>>(cnt, bsum, rowptr, dinv, cur, col);
    k_fill<<<gE, 256, 0, stream>>>(ei, rowptr, cur, col);

    k_gemm1<<<N_NODES / 32, 256, 0, stream>>>(x, W1, dinv, xw1b);
    k_agg1<<<(N_NODES + 3) / 4, 256, 0, stream>>>(rowptr, col, xw1b, dinv, b1, h1b);
    k_gemm2<<<N_NODES / 32, 256, 0, stream>>>(h1b, W2, wsd, xw2b, a_s, a_d);
    k_agg2<<<(N_NODES + 3) / 4, 256, 0, stream>>>(rowptr, col, xw2b, a_s, a_d, b2, W3, dinv, xw3);
    k_agg3<<<(N_NODES + 255) / 256, 256, 0, stream>>>(rowptr, col, xw3, dinv, b3, out);
}